// Round 2
// baseline (395.466 us; speedup 1.0000x reference)
//
#include <hip/hip_runtime.h>

typedef unsigned short u16;
typedef __bf16 bf16x8 __attribute__((ext_vector_type(8)));
typedef float f32x4 __attribute__((ext_vector_type(4)));
typedef u16 u16x4 __attribute__((ext_vector_type(4)));
typedef u16 u16x8 __attribute__((ext_vector_type(8)));

#define MFMA_B16(a, b, c) __builtin_amdgcn_mfma_f32_16x16x32_bf16((a), (b), (c), 0, 0, 0)

__device__ __forceinline__ u16 f2b(float f) {
  unsigned int b = __builtin_bit_cast(unsigned int, f);
  b += 0x7FFFu + ((b >> 16) & 1u);
  return (u16)(b >> 16);
}

__device__ __forceinline__ void gload16(const void* g, void* l) {
  __builtin_amdgcn_global_load_lds(
      (const __attribute__((address_space(1))) unsigned int*)g,
      (__attribute__((address_space(3))) unsigned int*)l, 16, 0, 0);
}

// ---------------- cast f32 -> bf16 (grid-stride, float4) ----------------
__global__ void k_cast(const float* __restrict__ s, u16* __restrict__ d, int n) {
  int i = blockIdx.x * blockDim.x + threadIdx.x;
  const int stride = gridDim.x * blockDim.x;
  const int n4 = n >> 2;
  for (; i < n4; i += stride) {
    f32x4 v = *(const f32x4*)(s + (size_t)i * 4);
    u16x4 o = {f2b(v[0]), f2b(v[1]), f2b(v[2]), f2b(v[3])};
    *(u16x4*)(d + (size_t)i * 4) = o;
  }
}

// ---- cast x -> bf16 + LoRA t = x @ A^T (f32, one wave per row) ----
__global__ void k_prep_x(const float* __restrict__ x, const float* __restrict__ qa,
                         const float* __restrict__ va, u16* __restrict__ xb,
                         float* __restrict__ tq, float* __restrict__ tv) {
  const int gw = (blockIdx.x * blockDim.x + threadIdx.x) >> 6;  // row index 0..8191
  const int lane = threadIdx.x & 63;
  const float* xr = x + (size_t)gw * 1024;
  u16* xo = xb + (size_t)gw * 1024;
  float acc[16];
#pragma unroll
  for (int r = 0; r < 16; ++r) acc[r] = 0.f;
#pragma unroll
  for (int p = 0; p < 4; ++p) {
    const int c = p * 256 + lane * 4;
    f32x4 v = *(const f32x4*)(xr + c);
    u16x4 o = {f2b(v[0]), f2b(v[1]), f2b(v[2]), f2b(v[3])};
    *(u16x4*)(xo + c) = o;
#pragma unroll
    for (int r = 0; r < 8; ++r) {
      const float* qr = qa + r * 1024 + c;
      const float* vr = va + r * 1024 + c;
      acc[r]     += v[0] * qr[0] + v[1] * qr[1] + v[2] * qr[2] + v[3] * qr[3];
      acc[r + 8] += v[0] * vr[0] + v[1] * vr[1] + v[2] * vr[2] + v[3] * vr[3];
    }
  }
#pragma unroll
  for (int r = 0; r < 16; ++r) {
#pragma unroll
    for (int off = 1; off < 64; off <<= 1) acc[r] += __shfl_xor(acc[r], off, 64);
  }
  if (lane < 8) tq[gw * 8 + lane] = acc[lane];
  else if (lane < 16) tv[gw * 8 + (lane - 8)] = acc[lane];
}

// ---------------- QKV GEMM (m97-style) + bias + LoRA + scatter ----------------
// A = x bf16 [8192][1024], Bw = qkv_w bf16 [3072][1024] (K-fast, i.e. B^T GEMM)
// Writes Q (pre-scaled by 0.125*log2e), K, V as bf16 [B,H,N,D]
__global__ __launch_bounds__(256, 2)
void k_qkv(const u16* __restrict__ A, const u16* __restrict__ Bw,
           const float* __restrict__ bias,
           const float* __restrict__ tq, const float* __restrict__ tv,
           const float* __restrict__ lqb, const float* __restrict__ lvb,
           u16* __restrict__ Qo, u16* __restrict__ Ko, u16* __restrict__ Vo) {
  __shared__ alignas(16) u16 lA[128 * 64];
  __shared__ alignas(16) u16 lB[128 * 64];
  const int t = threadIdx.x;
  const int w = t >> 6, lane = t & 63;
  const int wr = w >> 1, wc = w & 1;
  const int bm = blockIdx.x & 63, bn = blockIdx.x >> 6;  // 64 x 24
  const int rowg = bm * 128, colg = bn * 128;
  const int srow = t >> 3, scol = (t & 7) * 8;

  f32x4 acc[4][4];
#pragma unroll
  for (int i = 0; i < 4; ++i)
#pragma unroll
    for (int j = 0; j < 4; ++j) acc[i][j] = 0.0f;

  for (int kt = 0; kt < 16; ++kt) {
#pragma unroll
    for (int c = 0; c < 4; ++c) {
      const int row = c * 32 + srow;
      gload16(A + (size_t)(rowg + row) * 1024 + kt * 64 + scol, &lA[row * 64 + scol]);
      gload16(Bw + (size_t)(colg + row) * 1024 + kt * 64 + scol, &lB[row * 64 + scol]);
    }
    __syncthreads();
#pragma unroll
    for (int kk = 0; kk < 2; ++kk) {
      bf16x8 af[4], bfr[4];
#pragma unroll
      for (int i = 0; i < 4; ++i) {
        af[i]  = *(const bf16x8*)&lA[(wr * 64 + i * 16 + (lane & 15)) * 64 + kk * 32 + (lane >> 4) * 8];
        bfr[i] = *(const bf16x8*)&lB[(wc * 64 + i * 16 + (lane & 15)) * 64 + kk * 32 + (lane >> 4) * 8];
      }
#pragma unroll
      for (int i = 0; i < 4; ++i)
#pragma unroll
        for (int j = 0; j < 4; ++j) acc[i][j] = MFMA_B16(af[i], bfr[j], acc[i][j]);
    }
    __syncthreads();
  }

  // epilogue: stage t rows + lora_b cols in LDS (reuse tiles)
  const int sec = bn >> 3;  // 0=q 1=k 2=v
  float* lT = (float*)lA;   // [128][8]
  float* lLB = (float*)lB;  // [128][8]
  const float* tvec = (sec == 2) ? tv : tq;
  const float* lb = (sec == 2) ? lvb : lqb;
  if (t < 128) {
    const float* s = tvec + (size_t)(rowg + t) * 8;
    *(f32x4*)&lT[t * 8] = *(const f32x4*)s;
    *(f32x4*)&lT[t * 8 + 4] = *(const f32x4*)(s + 4);
  } else {
    const int cc = t - 128;
    const float* s = lb + (size_t)((colg & 1023) + cc) * 8;
    *(f32x4*)&lLB[cc * 8] = *(const f32x4*)s;
    *(f32x4*)&lLB[cc * 8 + 4] = *(const f32x4*)(s + 4);
  }
  __syncthreads();

  const float SQ = 0.18033688011112042f;  // 0.125 * log2(e), folded into Q
  float bvl[4], lbc[4][8];
  int cll[4];
#pragma unroll
  for (int j = 0; j < 4; ++j) {
    cll[j] = wc * 64 + j * 16 + (lane & 15);
    bvl[j] = bias[colg + cll[j]];
#pragma unroll
    for (int r = 0; r < 8; ++r) lbc[j][r] = lLB[cll[j] * 8 + r];
  }
  u16* outp = (sec == 0) ? Qo : ((sec == 1) ? Ko : Vo);
#pragma unroll
  for (int i = 0; i < 4; ++i) {
#pragma unroll
    for (int rg = 0; rg < 4; ++rg) {
      const int rl = wr * 64 + i * 16 + (lane >> 4) * 4 + rg;
      const int grow = rowg + rl;
      const int bb = grow >> 10, nidx = grow & 1023;
      float tr[8];
      if (sec != 1) {
#pragma unroll
        for (int r = 0; r < 8; ++r) tr[r] = lT[rl * 8 + r];
      }
#pragma unroll
      for (int j = 0; j < 4; ++j) {
        float v = acc[i][j][rg] + bvl[j];
        if (sec != 1) {
          float ad = 0.f;
#pragma unroll
          for (int r = 0; r < 8; ++r) ad += tr[r] * lbc[j][r];
          v += 2.0f * ad;
        }
        if (sec == 0) v *= SQ;
        const int c1024 = (colg & 1023) + cll[j];
        const int h = c1024 >> 6, d = c1024 & 63;
        outp[(size_t)((bb * 16 + h) * 1024 + nidx) * 64 + d] = f2b(v);
      }
    }
  }
}

// ---------------- flash attention: 1 block = 1 (b,h) x 128 q rows ----------------
__global__ __launch_bounds__(256, 2)
void k_attn(const u16* __restrict__ Qb, const u16* __restrict__ Kb,
            const u16* __restrict__ Vb, u16* __restrict__ att) {
  __shared__ alignas(16) u16 lsP[128 * 128];  // P tile (also Q staging at start)
  __shared__ alignas(16) u16 lsK[128 * 64];
  __shared__ alignas(16) u16 lsVT[64 * 128];  // V transposed [d][kv]
  const int t = threadIdx.x, w = t >> 6, lane = t & 63;
  const int bh = blockIdx.x >> 3, qt = blockIdx.x & 7;
  const u16* Qg = Qb + (size_t)bh * 65536;
  const u16* Kg = Kb + (size_t)bh * 65536;
  const u16* Vg = Vb + (size_t)bh * 65536;
  const int srow = t >> 3, scol = (t & 7) * 8;

#pragma unroll
  for (int c = 0; c < 4; ++c) {
    const int row = c * 32 + srow;
    gload16(Qg + (size_t)(qt * 128 + row) * 64 + scol, &lsP[row * 64 + scol]);
  }
  __syncthreads();
  bf16x8 qf[2][2];
#pragma unroll
  for (int mf = 0; mf < 2; ++mf)
#pragma unroll
    for (int kk = 0; kk < 2; ++kk)
      qf[mf][kk] = *(const bf16x8*)&lsP[(w * 32 + mf * 16 + (lane & 15)) * 64 + kk * 32 + (lane >> 4) * 8];

  float mi[2][4], li[2][4];
  f32x4 oacc[2][4];
#pragma unroll
  for (int mf = 0; mf < 2; ++mf) {
#pragma unroll
    for (int rg = 0; rg < 4; ++rg) { mi[mf][rg] = -1e30f; li[mf][rg] = 0.f; }
#pragma unroll
    for (int df = 0; df < 4; ++df) oacc[mf][df] = 0.0f;
  }

  for (int kt = 0; kt < 8; ++kt) {
#pragma unroll
    for (int c = 0; c < 4; ++c) {
      const int row = c * 32 + srow;
      gload16(Kg + (size_t)(kt * 128 + row) * 64 + scol, &lsK[row * 64 + scol]);
    }
#pragma unroll
    for (int p = 0; p < 4; ++p) {
      const int kv = p * 32 + srow;
      u16x8 vv = *(const u16x8*)(Vg + (size_t)(kt * 128 + kv) * 64 + scol);
#pragma unroll
      for (int i = 0; i < 8; ++i) lsVT[(scol + i) * 128 + kv] = vv[i];
    }
    __syncthreads();

    // S = Q K^T (Q pre-scaled so S is in exp2 domain)
    f32x4 sacc[2][8];
#pragma unroll
    for (int mf = 0; mf < 2; ++mf)
#pragma unroll
      for (int nf = 0; nf < 8; ++nf) sacc[mf][nf] = 0.0f;
#pragma unroll
    for (int kk = 0; kk < 2; ++kk) {
#pragma unroll
      for (int nf = 0; nf < 8; ++nf) {
        bf16x8 kf = *(const bf16x8*)&lsK[(nf * 16 + (lane & 15)) * 64 + kk * 32 + (lane >> 4) * 8];
#pragma unroll
        for (int mf = 0; mf < 2; ++mf) sacc[mf][nf] = MFMA_B16(qf[mf][kk], kf, sacc[mf][nf]);
      }
    }

    // online softmax (rows live in 16-lane groups sharing lane>>4)
#pragma unroll
    for (int mf = 0; mf < 2; ++mf) {
#pragma unroll
      for (int rg = 0; rg < 4; ++rg) {
        float mx = sacc[mf][0][rg];
#pragma unroll
        for (int nf = 1; nf < 8; ++nf) mx = fmaxf(mx, sacc[mf][nf][rg]);
#pragma unroll
        for (int off = 1; off < 16; off <<= 1) mx = fmaxf(mx, __shfl_xor(mx, off, 64));
        const float mnew = fmaxf(mi[mf][rg], mx);
        const float alpha = exp2f(mi[mf][rg] - mnew);
        float rs = 0.f;
#pragma unroll
        for (int nf = 0; nf < 8; ++nf) {
          const float p = exp2f(sacc[mf][nf][rg] - mnew);
          sacc[mf][nf][rg] = p;
          rs += p;
        }
#pragma unroll
        for (int off = 1; off < 16; off <<= 1) rs += __shfl_xor(rs, off, 64);
        li[mf][rg] = li[mf][rg] * alpha + rs;
        mi[mf][rg] = mnew;
#pragma unroll
        for (int df = 0; df < 4; ++df) oacc[mf][df][rg] *= alpha;
      }
    }

    // P -> LDS bf16 (own-wave region only; no cross-wave hazard)
#pragma unroll
    for (int mf = 0; mf < 2; ++mf)
#pragma unroll
      for (int nf = 0; nf < 8; ++nf)
#pragma unroll
        for (int rg = 0; rg < 4; ++rg)
          lsP[(w * 32 + mf * 16 + (lane >> 4) * 4 + rg) * 128 + nf * 16 + (lane & 15)] =
              f2b(sacc[mf][nf][rg]);

    asm volatile("s_waitcnt lgkmcnt(0)" ::: "memory");

    // O += P V
    bf16x8 pa[2][4];
#pragma unroll
    for (int mf = 0; mf < 2; ++mf)
#pragma unroll
      for (int kk = 0; kk < 4; ++kk)
        pa[mf][kk] = *(const bf16x8*)&lsP[(w * 32 + mf * 16 + (lane & 15)) * 128 + kk * 32 + (lane >> 4) * 8];
#pragma unroll
    for (int df = 0; df < 4; ++df) {
#pragma unroll
      for (int kk = 0; kk < 4; ++kk) {
        bf16x8 vf = *(const bf16x8*)&lsVT[(df * 16 + (lane & 15)) * 128 + kk * 32 + (lane >> 4) * 8];
#pragma unroll
        for (int mf = 0; mf < 2; ++mf) oacc[mf][df] = MFMA_B16(pa[mf][kk], vf, oacc[mf][df]);
      }
    }
    __syncthreads();
  }

  const int bb = bh >> 4, h = bh & 15;
#pragma unroll
  for (int mf = 0; mf < 2; ++mf) {
#pragma unroll
    for (int rg = 0; rg < 4; ++rg) {
      const float rl = 1.0f / li[mf][rg];
      const int qrow = qt * 128 + w * 32 + mf * 16 + (lane >> 4) * 4 + rg;
      const size_t base = ((size_t)(bb * 1024 + qrow)) * 1024 + h * 64;
#pragma unroll
      for (int df = 0; df < 4; ++df)
        att[base + df * 16 + (lane & 15)] = f2b(oacc[mf][df][rg] * rl);
    }
  }
}

// ---------------- proj GEMM: out = att @ proj_w^T + proj_b (f32 out) ----------------
__global__ __launch_bounds__(256, 2)
void k_proj(const u16* __restrict__ A, const u16* __restrict__ Bw,
            const float* __restrict__ bias, float* __restrict__ out) {
  __shared__ alignas(16) u16 lA[128 * 64];
  __shared__ alignas(16) u16 lB[128 * 64];
  const int t = threadIdx.x;
  const int w = t >> 6, lane = t & 63;
  const int wr = w >> 1, wc = w & 1;
  const int bm = blockIdx.x & 63, bn = blockIdx.x >> 6;  // 64 x 8
  const int rowg = bm * 128, colg = bn * 128;
  const int srow = t >> 3, scol = (t & 7) * 8;

  f32x4 acc[4][4];
#pragma unroll
  for (int i = 0; i < 4; ++i)
#pragma unroll
    for (int j = 0; j < 4; ++j) acc[i][j] = 0.0f;

  for (int kt = 0; kt < 16; ++kt) {
#pragma unroll
    for (int c = 0; c < 4; ++c) {
      const int row = c * 32 + srow;
      gload16(A + (size_t)(rowg + row) * 1024 + kt * 64 + scol, &lA[row * 64 + scol]);
      gload16(Bw + (size_t)(colg + row) * 1024 + kt * 64 + scol, &lB[row * 64 + scol]);
    }
    __syncthreads();
#pragma unroll
    for (int kk = 0; kk < 2; ++kk) {
      bf16x8 af[4], bfr[4];
#pragma unroll
      for (int i = 0; i < 4; ++i) {
        af[i]  = *(const bf16x8*)&lA[(wr * 64 + i * 16 + (lane & 15)) * 64 + kk * 32 + (lane >> 4) * 8];
        bfr[i] = *(const bf16x8*)&lB[(wc * 64 + i * 16 + (lane & 15)) * 64 + kk * 32 + (lane >> 4) * 8];
      }
#pragma unroll
      for (int i = 0; i < 4; ++i)
#pragma unroll
        for (int j = 0; j < 4; ++j) acc[i][j] = MFMA_B16(af[i], bfr[j], acc[i][j]);
    }
    __syncthreads();
  }

#pragma unroll
  for (int i = 0; i < 4; ++i) {
#pragma unroll
    for (int rg = 0; rg < 4; ++rg) {
      const int grow = rowg + wr * 64 + i * 16 + (lane >> 4) * 4 + rg;
#pragma unroll
      for (int j = 0; j < 4; ++j) {
        const int cl = wc * 64 + j * 16 + (lane & 15);
        out[(size_t)grow * 1024 + colg + cl] = acc[i][j][rg] + bias[colg + cl];
      }
    }
  }
}

extern "C" void kernel_launch(void* const* d_in, const int* in_sizes, int n_in,
                              void* d_out, int out_size, void* d_ws, size_t ws_size,
                              hipStream_t stream) {
  (void)in_sizes; (void)n_in; (void)out_size; (void)ws_size;
  const float* x      = (const float*)d_in[0];
  const float* qkv_w  = (const float*)d_in[1];
  const float* qkv_b  = (const float*)d_in[2];
  const float* proj_w = (const float*)d_in[3];
  const float* proj_b = (const float*)d_in[4];
  const float* lqa    = (const float*)d_in[5];
  const float* lqb    = (const float*)d_in[6];
  const float* lva    = (const float*)d_in[7];
  const float* lvb    = (const float*)d_in[8];
  float* out = (float*)d_out;
  char* ws = (char*)d_ws;

  u16* xb    = (u16*)(ws);                              // 16 MiB
  u16* wqkv  = (u16*)(ws + (size_t)(16u << 20));        // 6 MiB
  u16* wproj = (u16*)(ws + (size_t)(22u << 20));        // 2 MiB
  float* tq  = (float*)(ws + (size_t)(24u << 20));      // 256 KiB
  float* tv  = (float*)(ws + (size_t)(24u << 20) + (256u << 10));
  u16* Qb    = (u16*)(ws + (size_t)(25u << 20));        // 16 MiB
  u16* Kb    = (u16*)(ws + (size_t)(41u << 20));        // 16 MiB
  u16* Vb    = (u16*)(ws + (size_t)(57u << 20));        // 16 MiB
  u16* att   = (u16*)(ws + (size_t)(73u << 20));        // 16 MiB (ends at 89 MiB)

  k_cast<<<dim3(1024), dim3(256), 0, stream>>>(qkv_w, wqkv, 3072 * 1024);
  k_cast<<<dim3(512), dim3(256), 0, stream>>>(proj_w, wproj, 1024 * 1024);
  k_prep_x<<<dim3(2048), dim3(256), 0, stream>>>(x, lqa, lva, xb, tq, tv);
  k_qkv<<<dim3(1536), dim3(256), 0, stream>>>(xb, wqkv, qkv_b, tq, tv, lqb, lvb, Qb, Kb, Vb);
  k_attn<<<dim3(1024), dim3(256), 0, stream>>>(Qb, Kb, Vb, att);
  k_proj<<<dim3(512), dim3(256), 0, stream>>>(att, wproj, proj_b, out);
}

// Round 3
// 387.703 us; speedup vs baseline: 1.0200x; 1.0200x over previous
//
#include <hip/hip_runtime.h>

typedef unsigned short u16;
typedef __bf16 bf16x8 __attribute__((ext_vector_type(8)));
typedef float f32x4 __attribute__((ext_vector_type(4)));
typedef u16 u16x4 __attribute__((ext_vector_type(4)));
typedef u16 u16x8 __attribute__((ext_vector_type(8)));

#define MFMA_B16(a, b, c) __builtin_amdgcn_mfma_f32_16x16x32_bf16((a), (b), (c), 0, 0, 0)

__device__ __forceinline__ u16 f2b(float f) {
  unsigned int b = __builtin_bit_cast(unsigned int, f);
  b += 0x7FFFu + ((b >> 16) & 1u);
  return (u16)(b >> 16);
}

__device__ __forceinline__ void gload16(const void* g, void* l) {
  __builtin_amdgcn_global_load_lds(
      (const __attribute__((address_space(1))) unsigned int*)g,
      (__attribute__((address_space(3))) unsigned int*)l, 16, 0, 0);
}

// ---- LDS swizzles (element-index space; 16B unit = 8 u16) ----
// [*][64] tiles (K, staged Q): col ^= (row&7)<<3. Staged via gload_lds with
// pre-swizzled GLOBAL source unit (dest stays linear: both-sides rule).
__device__ __forceinline__ int swzK(int row, int col) {
  return row * 64 + (col ^ ((row & 7) << 3));
}
// P tile [128][128]
__device__ __forceinline__ int swzP(int row, int col) {
  return row * 128 + (col ^ ((row & 7) << 3));
}
// VT tile [64 d][128 kv]: key (d&7)^((d>>3)&7) — transpose-write lanes vary d>>3,
// frag-read lanes vary d&7; both spread across 8 slots, residual <=2-way (free).
__device__ __forceinline__ int swzV(int d, int kv) {
  return d * 128 + (kv ^ ((((d >> 3) ^ d) & 7) << 3));
}

// ---------------- cast f32 -> bf16 (grid-stride, float4) ----------------
__global__ void k_cast(const float* __restrict__ s, u16* __restrict__ d, int n) {
  int i = blockIdx.x * blockDim.x + threadIdx.x;
  const int stride = gridDim.x * blockDim.x;
  const int n4 = n >> 2;
  for (; i < n4; i += stride) {
    f32x4 v = *(const f32x4*)(s + (size_t)i * 4);
    u16x4 o = {f2b(v[0]), f2b(v[1]), f2b(v[2]), f2b(v[3])};
    *(u16x4*)(d + (size_t)i * 4) = o;
  }
}

// ---- cast x -> bf16 + LoRA t = x @ A^T (f32, one wave per row) ----
__global__ void k_prep_x(const float* __restrict__ x, const float* __restrict__ qa,
                         const float* __restrict__ va, u16* __restrict__ xb,
                         float* __restrict__ tq, float* __restrict__ tv) {
  const int gw = (blockIdx.x * blockDim.x + threadIdx.x) >> 6;  // row index 0..8191
  const int lane = threadIdx.x & 63;
  const float* xr = x + (size_t)gw * 1024;
  u16* xo = xb + (size_t)gw * 1024;
  float acc[16];
#pragma unroll
  for (int r = 0; r < 16; ++r) acc[r] = 0.f;
#pragma unroll
  for (int p = 0; p < 4; ++p) {
    const int c = p * 256 + lane * 4;
    f32x4 v = *(const f32x4*)(xr + c);
    u16x4 o = {f2b(v[0]), f2b(v[1]), f2b(v[2]), f2b(v[3])};
    *(u16x4*)(xo + c) = o;
#pragma unroll
    for (int r = 0; r < 8; ++r) {
      const float* qr = qa + r * 1024 + c;
      const float* vr = va + r * 1024 + c;
      acc[r]     += v[0] * qr[0] + v[1] * qr[1] + v[2] * qr[2] + v[3] * qr[3];
      acc[r + 8] += v[0] * vr[0] + v[1] * vr[1] + v[2] * vr[2] + v[3] * vr[3];
    }
  }
#pragma unroll
  for (int r = 0; r < 16; ++r) {
#pragma unroll
    for (int off = 1; off < 64; off <<= 1) acc[r] += __shfl_xor(acc[r], off, 64);
  }
  if (lane < 8) tq[gw * 8 + lane] = acc[lane];
  else if (lane < 16) tv[gw * 8 + (lane - 8)] = acc[lane];
}

// ---------------- QKV GEMM (m97-style) + bias + LoRA + scatter ----------------
__global__ __launch_bounds__(256, 2)
void k_qkv(const u16* __restrict__ A, const u16* __restrict__ Bw,
           const float* __restrict__ bias,
           const float* __restrict__ tq, const float* __restrict__ tv,
           const float* __restrict__ lqb, const float* __restrict__ lvb,
           u16* __restrict__ Qo, u16* __restrict__ Ko, u16* __restrict__ Vo) {
  __shared__ alignas(16) u16 lA[128 * 64];
  __shared__ alignas(16) u16 lB[128 * 64];
  const int t = threadIdx.x;
  const int w = t >> 6, lane = t & 63;
  const int wr = w >> 1, wc = w & 1;
  const int bm = blockIdx.x & 63, bn = blockIdx.x >> 6;  // 64 x 24
  const int rowg = bm * 128, colg = bn * 128;
  const int srow = t >> 3, scol = (t & 7) * 8;

  f32x4 acc[4][4];
#pragma unroll
  for (int i = 0; i < 4; ++i)
#pragma unroll
    for (int j = 0; j < 4; ++j) acc[i][j] = 0.0f;

  for (int kt = 0; kt < 16; ++kt) {
#pragma unroll
    for (int c = 0; c < 4; ++c) {
      const int row = c * 32 + srow;
      gload16(A + (size_t)(rowg + row) * 1024 + kt * 64 + scol, &lA[row * 64 + scol]);
      gload16(Bw + (size_t)(colg + row) * 1024 + kt * 64 + scol, &lB[row * 64 + scol]);
    }
    __syncthreads();
#pragma unroll
    for (int kk = 0; kk < 2; ++kk) {
      bf16x8 af[4], bfr[4];
#pragma unroll
      for (int i = 0; i < 4; ++i) {
        af[i]  = *(const bf16x8*)&lA[(wr * 64 + i * 16 + (lane & 15)) * 64 + kk * 32 + (lane >> 4) * 8];
        bfr[i] = *(const bf16x8*)&lB[(wc * 64 + i * 16 + (lane & 15)) * 64 + kk * 32 + (lane >> 4) * 8];
      }
#pragma unroll
      for (int i = 0; i < 4; ++i)
#pragma unroll
        for (int j = 0; j < 4; ++j) acc[i][j] = MFMA_B16(af[i], bfr[j], acc[i][j]);
    }
    __syncthreads();
  }

  // epilogue: stage t rows + lora_b cols in LDS (reuse tiles)
  const int sec = bn >> 3;  // 0=q 1=k 2=v
  float* lT = (float*)lA;   // [128][8]
  float* lLB = (float*)lB;  // [128][8]
  const float* tvec = (sec == 2) ? tv : tq;
  const float* lb = (sec == 2) ? lvb : lqb;
  if (t < 128) {
    const float* s = tvec + (size_t)(rowg + t) * 8;
    *(f32x4*)&lT[t * 8] = *(const f32x4*)s;
    *(f32x4*)&lT[t * 8 + 4] = *(const f32x4*)(s + 4);
  } else {
    const int cc = t - 128;
    const float* s = lb + (size_t)((colg & 1023) + cc) * 8;
    *(f32x4*)&lLB[cc * 8] = *(const f32x4*)s;
    *(f32x4*)&lLB[cc * 8 + 4] = *(const f32x4*)(s + 4);
  }
  __syncthreads();

  const float SQ = 0.18033688011112042f;  // 0.125 * log2(e), folded into Q
  float bvl[4], lbc[4][8];
  int cll[4];
#pragma unroll
  for (int j = 0; j < 4; ++j) {
    cll[j] = wc * 64 + j * 16 + (lane & 15);
    bvl[j] = bias[colg + cll[j]];
#pragma unroll
    for (int r = 0; r < 8; ++r) lbc[j][r] = lLB[cll[j] * 8 + r];
  }
  u16* outp = (sec == 0) ? Qo : ((sec == 1) ? Ko : Vo);
#pragma unroll
  for (int i = 0; i < 4; ++i) {
#pragma unroll
    for (int rg = 0; rg < 4; ++rg) {
      const int rl = wr * 64 + i * 16 + (lane >> 4) * 4 + rg;
      const int grow = rowg + rl;
      const int bb = grow >> 10, nidx = grow & 1023;
      float tr[8];
      if (sec != 1) {
#pragma unroll
        for (int r = 0; r < 8; ++r) tr[r] = lT[rl * 8 + r];
      }
#pragma unroll
      for (int j = 0; j < 4; ++j) {
        float v = acc[i][j][rg] + bvl[j];
        if (sec != 1) {
          float ad = 0.f;
#pragma unroll
          for (int r = 0; r < 8; ++r) ad += tr[r] * lbc[j][r];
          v += 2.0f * ad;
        }
        if (sec == 0) v *= SQ;
        const int c1024 = (colg & 1023) + cll[j];
        const int h = c1024 >> 6, d = c1024 & 63;
        outp[(size_t)((bb * 16 + h) * 1024 + nidx) * 64 + d] = f2b(v);
      }
    }
  }
}

// ---------------- flash attention: 1 block = 1 (b,h) x 128 q rows ----------------
// All LDS tiles XOR-swizzled (T2). K/Q staged via gload_lds with pre-swizzled
// global source unit; P and VT swizzled on both write and read.
__global__ __launch_bounds__(256, 2)
void k_attn(const u16* __restrict__ Qb, const u16* __restrict__ Kb,
            const u16* __restrict__ Vb, u16* __restrict__ att) {
  __shared__ alignas(16) u16 lsP[128 * 128];  // P tile (also Q staging at start)
  __shared__ alignas(16) u16 lsK[128 * 64];
  __shared__ alignas(16) u16 lsVT[64 * 128];  // V transposed [d][kv]
  const int t = threadIdx.x, w = t >> 6, lane = t & 63;
  const int bh = blockIdx.x >> 3, qt = blockIdx.x & 7;
  const u16* Qg = Qb + (size_t)bh * 65536;
  const u16* Kg = Kb + (size_t)bh * 65536;
  const u16* Vg = Vb + (size_t)bh * 65536;
  const int srow = t >> 3, scol = (t & 7) * 8;
  // pre-swizzled global source unit for gload_lds staging (row&7 == (t>>3)&7)
  const int srcc = (((t & 7) ^ (t >> 3)) & 7) * 8;

#pragma unroll
  for (int c = 0; c < 4; ++c) {
    const int row = c * 32 + srow;
    gload16(Qg + (size_t)(qt * 128 + row) * 64 + srcc, &lsP[row * 64 + scol]);
  }
  __syncthreads();
  bf16x8 qf[2][2];
#pragma unroll
  for (int mf = 0; mf < 2; ++mf)
#pragma unroll
    for (int kk = 0; kk < 2; ++kk)
      qf[mf][kk] = *(const bf16x8*)&lsP[swzK(w * 32 + mf * 16 + (lane & 15),
                                             kk * 32 + (lane >> 4) * 8)];

  float mi[2][4], li[2][4];
  f32x4 oacc[2][4];
#pragma unroll
  for (int mf = 0; mf < 2; ++mf) {
#pragma unroll
    for (int rg = 0; rg < 4; ++rg) { mi[mf][rg] = -1e30f; li[mf][rg] = 0.f; }
#pragma unroll
    for (int df = 0; df < 4; ++df) oacc[mf][df] = 0.0f;
  }

  for (int kt = 0; kt < 8; ++kt) {
#pragma unroll
    for (int c = 0; c < 4; ++c) {
      const int row = c * 32 + srow;
      gload16(Kg + (size_t)(kt * 128 + row) * 64 + srcc, &lsK[row * 64 + scol]);
    }
#pragma unroll
    for (int p = 0; p < 4; ++p) {
      const int kv = p * 32 + srow;
      u16x8 vv = *(const u16x8*)(Vg + (size_t)(kt * 128 + kv) * 64 + scol);
#pragma unroll
      for (int i = 0; i < 8; ++i) lsVT[swzV(scol + i, kv)] = vv[i];
    }
    __syncthreads();

    // S = Q K^T (Q pre-scaled so S is in exp2 domain)
    f32x4 sacc[2][8];
#pragma unroll
    for (int mf = 0; mf < 2; ++mf)
#pragma unroll
      for (int nf = 0; nf < 8; ++nf) sacc[mf][nf] = 0.0f;
#pragma unroll
    for (int kk = 0; kk < 2; ++kk) {
#pragma unroll
      for (int nf = 0; nf < 8; ++nf) {
        bf16x8 kf = *(const bf16x8*)&lsK[swzK(nf * 16 + (lane & 15),
                                              kk * 32 + (lane >> 4) * 8)];
#pragma unroll
        for (int mf = 0; mf < 2; ++mf) sacc[mf][nf] = MFMA_B16(qf[mf][kk], kf, sacc[mf][nf]);
      }
    }

    // online softmax (rows live in 16-lane groups sharing lane>>4)
#pragma unroll
    for (int mf = 0; mf < 2; ++mf) {
#pragma unroll
      for (int rg = 0; rg < 4; ++rg) {
        float mx = sacc[mf][0][rg];
#pragma unroll
        for (int nf = 1; nf < 8; ++nf) mx = fmaxf(mx, sacc[mf][nf][rg]);
#pragma unroll
        for (int off = 1; off < 16; off <<= 1) mx = fmaxf(mx, __shfl_xor(mx, off, 64));
        const float mnew = fmaxf(mi[mf][rg], mx);
        const float alpha = exp2f(mi[mf][rg] - mnew);
        float rs = 0.f;
#pragma unroll
        for (int nf = 0; nf < 8; ++nf) {
          const float p = exp2f(sacc[mf][nf][rg] - mnew);
          sacc[mf][nf][rg] = p;
          rs += p;
        }
#pragma unroll
        for (int off = 1; off < 16; off <<= 1) rs += __shfl_xor(rs, off, 64);
        li[mf][rg] = li[mf][rg] * alpha + rs;
        mi[mf][rg] = mnew;
#pragma unroll
        for (int df = 0; df < 4; ++df) oacc[mf][df][rg] *= alpha;
      }
    }

    // P -> LDS bf16 (own-wave region only; no cross-wave hazard), swizzled
#pragma unroll
    for (int mf = 0; mf < 2; ++mf)
#pragma unroll
      for (int nf = 0; nf < 8; ++nf)
#pragma unroll
        for (int rg = 0; rg < 4; ++rg)
          lsP[swzP(w * 32 + mf * 16 + (lane >> 4) * 4 + rg, nf * 16 + (lane & 15))] =
              f2b(sacc[mf][nf][rg]);

    asm volatile("s_waitcnt lgkmcnt(0)" ::: "memory");

    // O += P V
    bf16x8 pa[2][4];
#pragma unroll
    for (int mf = 0; mf < 2; ++mf)
#pragma unroll
      for (int kk = 0; kk < 4; ++kk)
        pa[mf][kk] = *(const bf16x8*)&lsP[swzP(w * 32 + mf * 16 + (lane & 15),
                                               kk * 32 + (lane >> 4) * 8)];
#pragma unroll
    for (int df = 0; df < 4; ++df) {
#pragma unroll
      for (int kk = 0; kk < 4; ++kk) {
        bf16x8 vf = *(const bf16x8*)&lsVT[swzV(df * 16 + (lane & 15),
                                               kk * 32 + (lane >> 4) * 8)];
#pragma unroll
        for (int mf = 0; mf < 2; ++mf) oacc[mf][df] = MFMA_B16(pa[mf][kk], vf, oacc[mf][df]);
      }
    }
    __syncthreads();
  }

  const int bb = bh >> 4, h = bh & 15;
#pragma unroll
  for (int mf = 0; mf < 2; ++mf) {
#pragma unroll
    for (int rg = 0; rg < 4; ++rg) {
      const float rl = 1.0f / li[mf][rg];
      const int qrow = qt * 128 + w * 32 + mf * 16 + (lane >> 4) * 4 + rg;
      const size_t base = ((size_t)(bb * 1024 + qrow)) * 1024 + h * 64;
#pragma unroll
      for (int df = 0; df < 4; ++df)
        att[base + df * 16 + (lane & 15)] = f2b(oacc[mf][df][rg] * rl);
    }
  }
}

// ---------------- proj GEMM: out = att @ proj_w^T + proj_b (f32 out) ----------------
__global__ __launch_bounds__(256, 2)
void k_proj(const u16* __restrict__ A, const u16* __restrict__ Bw,
            const float* __restrict__ bias, float* __restrict__ out) {
  __shared__ alignas(16) u16 lA[128 * 64];
  __shared__ alignas(16) u16 lB[128 * 64];
  const int t = threadIdx.x;
  const int w = t >> 6, lane = t & 63;
  const int wr = w >> 1, wc = w & 1;
  const int bm = blockIdx.x & 63, bn = blockIdx.x >> 6;  // 64 x 8
  const int rowg = bm * 128, colg = bn * 128;
  const int srow = t >> 3, scol = (t & 7) * 8;

  f32x4 acc[4][4];
#pragma unroll
  for (int i = 0; i < 4; ++i)
#pragma unroll
    for (int j = 0; j < 4; ++j) acc[i][j] = 0.0f;

  for (int kt = 0; kt < 16; ++kt) {
#pragma unroll
    for (int c = 0; c < 4; ++c) {
      const int row = c * 32 + srow;
      gload16(A + (size_t)(rowg + row) * 1024 + kt * 64 + scol, &lA[row * 64 + scol]);
      gload16(Bw + (size_t)(colg + row) * 1024 + kt * 64 + scol, &lB[row * 64 + scol]);
    }
    __syncthreads();
#pragma unroll
    for (int kk = 0; kk < 2; ++kk) {
      bf16x8 af[4], bfr[4];
#pragma unroll
      for (int i = 0; i < 4; ++i) {
        af[i]  = *(const bf16x8*)&lA[(wr * 64 + i * 16 + (lane & 15)) * 64 + kk * 32 + (lane >> 4) * 8];
        bfr[i] = *(const bf16x8*)&lB[(wc * 64 + i * 16 + (lane & 15)) * 64 + kk * 32 + (lane >> 4) * 8];
      }
#pragma unroll
      for (int i = 0; i < 4; ++i)
#pragma unroll
        for (int j = 0; j < 4; ++j) acc[i][j] = MFMA_B16(af[i], bfr[j], acc[i][j]);
    }
    __syncthreads();
  }

#pragma unroll
  for (int i = 0; i < 4; ++i) {
#pragma unroll
    for (int rg = 0; rg < 4; ++rg) {
      const int grow = rowg + wr * 64 + i * 16 + (lane >> 4) * 4 + rg;
#pragma unroll
      for (int j = 0; j < 4; ++j) {
        const int cl = wc * 64 + j * 16 + (lane & 15);
        out[(size_t)grow * 1024 + colg + cl] = acc[i][j][rg] + bias[colg + cl];
      }
    }
  }
}

extern "C" void kernel_launch(void* const* d_in, const int* in_sizes, int n_in,
                              void* d_out, int out_size, void* d_ws, size_t ws_size,
                              hipStream_t stream) {
  (void)in_sizes; (void)n_in; (void)out_size; (void)ws_size;
  const float* x      = (const float*)d_in[0];
  const float* qkv_w  = (const float*)d_in[1];
  const float* qkv_b  = (const float*)d_in[2];
  const float* proj_w = (const float*)d_in[3];
  const float* proj_b = (const float*)d_in[4];
  const float* lqa    = (const float*)d_in[5];
  const float* lqb    = (const float*)d_in[6];
  const float* lva    = (const float*)d_in[7];
  const float* lvb    = (const float*)d_in[8];
  float* out = (float*)d_out;
  char* ws = (char*)d_ws;

  u16* xb    = (u16*)(ws);                              // 16 MiB
  u16* wqkv  = (u16*)(ws + (size_t)(16u << 20));        // 6 MiB
  u16* wproj = (u16*)(ws + (size_t)(22u << 20));        // 2 MiB
  float* tq  = (float*)(ws + (size_t)(24u << 20));      // 256 KiB
  float* tv  = (float*)(ws + (size_t)(24u << 20) + (256u << 10));
  u16* Qb    = (u16*)(ws + (size_t)(25u << 20));        // 16 MiB
  u16* Kb    = (u16*)(ws + (size_t)(41u << 20));        // 16 MiB
  u16* Vb    = (u16*)(ws + (size_t)(57u << 20));        // 16 MiB
  u16* att   = (u16*)(ws + (size_t)(73u << 20));        // 16 MiB (ends at 89 MiB)

  k_cast<<<dim3(1024), dim3(256), 0, stream>>>(qkv_w, wqkv, 3072 * 1024);
  k_cast<<<dim3(512), dim3(256), 0, stream>>>(proj_w, wproj, 1024 * 1024);
  k_prep_x<<<dim3(2048), dim3(256), 0, stream>>>(x, lqa, lva, xb, tq, tv);
  k_qkv<<<dim3(1536), dim3(256), 0, stream>>>(xb, wqkv, qkv_b, tq, tv, lqb, lvb, Qb, Kb, Vb);
  k_attn<<<dim3(1024), dim3(256), 0, stream>>>(Qb, Kb, Vb, att);
  k_proj<<<dim3(512), dim3(256), 0, stream>>>(att, wproj, proj_b, out);
}